// Round 1
// baseline (26541.501 us; speedup 1.0000x reference)
//
#include <hip/hip_runtime.h>
#include <math.h>

#define B_   8
#define C_   64
#define N_   65536
#define R_   32
#define R3_  32768

// ---------------- helpers ----------------
__device__ inline void atomicMaxF(float* addr, float v) {
    // valid for non-negative floats (bit pattern is monotone)
    atomicMax((unsigned int*)addr, __float_as_uint(v));
}

// stats layout: stats[b*8 + {0,1,2}] = coord sums, stats[b*8+3] = max norm
__global__ __launch_bounds__(256) void k_stats_sum(const float* __restrict__ coords,
                                                   float* __restrict__ stats) {
    int b = blockIdx.y;
    int tid = threadIdx.x;
    const float* cb = coords + (size_t)b * 3 * N_;
    float sx = 0.f, sy = 0.f, sz = 0.f;
    int base = blockIdx.x * 2048;
    for (int k = 0; k < 8; ++k) {
        int n = base + k * 256 + tid;
        sx += cb[n];
        sy += cb[N_ + n];
        sz += cb[2 * N_ + n];
    }
    for (int o = 32; o > 0; o >>= 1) {
        sx += __shfl_down(sx, o);
        sy += __shfl_down(sy, o);
        sz += __shfl_down(sz, o);
    }
    if ((tid & 63) == 0) {
        atomicAdd(&stats[b * 8 + 0], sx);
        atomicAdd(&stats[b * 8 + 1], sy);
        atomicAdd(&stats[b * 8 + 2], sz);
    }
}

__global__ __launch_bounds__(256) void k_stats_max(const float* __restrict__ coords,
                                                   float* __restrict__ stats) {
    int b = blockIdx.y;
    int tid = threadIdx.x;
    const float* cb = coords + (size_t)b * 3 * N_;
    float mx = stats[b * 8 + 0] * (1.f / N_);
    float my = stats[b * 8 + 1] * (1.f / N_);
    float mz = stats[b * 8 + 2] * (1.f / N_);
    float vm = 0.f;
    int base = blockIdx.x * 2048;
    for (int k = 0; k < 8; ++k) {
        int n = base + k * 256 + tid;
        float dx = cb[n] - mx, dy = cb[N_ + n] - my, dz = cb[2 * N_ + n] - mz;
        vm = fmaxf(vm, sqrtf(dx * dx + dy * dy + dz * dz));
    }
    for (int o = 32; o > 0; o >>= 1) vm = fmaxf(vm, __shfl_down(vm, o));
    if ((tid & 63) == 0) atomicMaxF(&stats[b * 8 + 3], vm);
}

__global__ __launch_bounds__(256) void k_scatter(const float* __restrict__ feats,
                                                 const float* __restrict__ coords,
                                                 const float* __restrict__ stats,
                                                 float* __restrict__ voxsum,
                                                 float* __restrict__ cnt,
                                                 float* __restrict__ ncoords) {
    int p = blockIdx.x * 256 + threadIdx.x;
    int b = p >> 16, n = p & (N_ - 1);
    const float* cb = coords + (size_t)b * 3 * N_;
    float mx = stats[b * 8 + 0] * (1.f / N_);
    float my = stats[b * 8 + 1] * (1.f / N_);
    float mz = stats[b * 8 + 2] * (1.f / N_);
    float s2 = stats[b * 8 + 3] * 2.0f;
    float cv[3] = {cb[n] - mx, cb[N_ + n] - my, cb[2 * N_ + n] - mz};
    int id[3];
#pragma unroll
    for (int d = 0; d < 3; ++d) {
        float t = cv[d] / s2 + 0.5f;
        float nc = fminf(fmaxf(t * (float)R_, 0.f), (float)(R_ - 1));
        ncoords[((size_t)b * 3 + d) * N_ + n] = nc;
        id[d] = (int)rintf(nc);   // round-half-even == jnp.round
    }
    int vidx = id[0] * R_ * R_ + id[1] * R_ + id[2];
    atomicAdd(&cnt[(size_t)b * R3_ + vidx], 1.0f);
    float* vs = voxsum + (size_t)b * C_ * R3_ + vidx;
    const float* fb = feats + (size_t)b * C_ * N_ + n;
#pragma unroll 4
    for (int c = 0; c < C_; ++c)
        atomicAdd(&vs[(size_t)c * R3_], fb[(size_t)c * N_]);
}

// conv 3x3x3 SAME + bias + BN + SiLU. Block = (b,z-plane) x cout.
// DIV: input is voxel sums, divide by max(cnt,1) on load (fused voxel average).
template <bool DIV>
__global__ __launch_bounds__(256) void k_conv(const float* __restrict__ src,
                                              const float* __restrict__ cnt,
                                              const float* __restrict__ w,
                                              const float* __restrict__ bias,
                                              const float* __restrict__ g,
                                              const float* __restrict__ bb,
                                              const float* __restrict__ bm,
                                              const float* __restrict__ bv,
                                              float* __restrict__ dst) {
    __shared__ float tile[4][3][34][36];   // 58.75 KB
    int b = blockIdx.x >> 5, z = blockIdx.x & 31;
    int co = blockIdx.y;
    int tid = threadIdx.x;
    int ty = tid >> 3;            // 0..31 (y)
    int tx4 = (tid & 7) * 4;      // 0,4,...,28 (x base, 4 outputs each)
    float acc0 = 0.f, acc1 = 0.f, acc2 = 0.f, acc3 = 0.f;
    const float* sb = src + (size_t)b * C_ * R3_;
    const float* cb = cnt ? cnt + (size_t)b * R3_ : nullptr;

    for (int cg = 0; cg < 16; ++cg) {
        __syncthreads();
        for (int i = tid; i < 4 * 3 * 34 * 34; i += 256) {
            int ci = i / (3 * 34 * 34);
            int r1 = i - ci * (3 * 34 * 34);
            int zz = r1 / (34 * 34);
            int r2 = r1 - zz * (34 * 34);
            int yy = r2 / 34;
            int xx = r2 - yy * 34;
            int gz = z + zz - 1, gy = yy - 1, gx = xx - 1;
            float val = 0.f;
            if (((unsigned)gz < 32u) && ((unsigned)gy < 32u) && ((unsigned)gx < 32u)) {
                int sp = gz * 1024 + gy * 32 + gx;
                val = sb[(size_t)(cg * 4 + ci) * R3_ + sp];
                if (DIV) val = val / fmaxf(cb[sp], 1.0f);
            }
            tile[ci][zz][yy][xx] = val;
        }
        __syncthreads();
#pragma unroll
        for (int ci = 0; ci < 4; ++ci) {
#pragma unroll
            for (int dz = 0; dz < 3; ++dz) {
#pragma unroll
                for (int dy = 0; dy < 3; ++dy) {
                    const float* wp = w + ((((size_t)co * C_ + cg * 4 + ci) * 3 + dz) * 3 + dy) * 3;
                    float w0 = wp[0], w1 = wp[1], w2 = wp[2];
                    const float* row = &tile[ci][dz][ty + dy][tx4];
                    float4 a = *(const float4*)row;
                    float2 e = *(const float2*)(row + 4);
                    acc0 += a.x * w0 + a.y * w1 + a.z * w2;
                    acc1 += a.y * w0 + a.z * w1 + a.w * w2;
                    acc2 += a.z * w0 + a.w * w1 + e.x * w2;
                    acc3 += a.w * w0 + e.x * w1 + e.y * w2;
                }
            }
        }
    }
    float s = g[co] * rsqrtf(bv[co] + 1e-5f);
    float t = bb[co] - bm[co] * s;
    float cbias = bias[co];
    float r[4] = {acc0, acc1, acc2, acc3};
    float* dp = dst + ((size_t)b * C_ + co) * R3_ + z * 1024 + ty * 32 + tx4;
#pragma unroll
    for (int j = 0; j < 4; ++j) {
        float vv = (r[j] + cbias) * s + t;
        vv = vv / (1.0f + expf(-vv));   // SiLU
        dp[j] = vv;
    }
}

// devoxelize (trilinear) + point MLP + BN3 + ReLU + add
__global__ __launch_bounds__(256) void k_fuse(const float* __restrict__ x2,
                                              const float* __restrict__ ncoords,
                                              const float* __restrict__ feats,
                                              const float* __restrict__ mw,
                                              const float* __restrict__ mb,
                                              const float* __restrict__ g,
                                              const float* __restrict__ bb,
                                              const float* __restrict__ bm,
                                              const float* __restrict__ bv,
                                              float* __restrict__ out) {
    int p = blockIdx.x * 256 + threadIdx.x;
    int b = p >> 16, n = p & (N_ - 1);
    int cbase = blockIdx.y * 16;

    float nx = ncoords[((size_t)b * 3 + 0) * N_ + n];
    float ny = ncoords[((size_t)b * 3 + 1) * N_ + n];
    float nz = ncoords[((size_t)b * 3 + 2) * N_ + n];
    float flx = floorf(nx), fly = floorf(ny), flz = floorf(nz);
    float fx = nx - flx, fy = ny - fly, fz = nz - flz;
    int x0 = (int)flx, y0 = (int)fly, z0 = (int)flz;
    int x1 = min(x0 + 1, R_ - 1), y1 = min(y0 + 1, R_ - 1), z1 = min(z0 + 1, R_ - 1);
    int o000 = x0 * 1024 + y0 * 32 + z0;
    int o001 = x0 * 1024 + y0 * 32 + z1;
    int o010 = x0 * 1024 + y1 * 32 + z0;
    int o011 = x0 * 1024 + y1 * 32 + z1;
    int o100 = x1 * 1024 + y0 * 32 + z0;
    int o101 = x1 * 1024 + y0 * 32 + z1;
    int o110 = x1 * 1024 + y1 * 32 + z0;
    int o111 = x1 * 1024 + y1 * 32 + z1;
    float w000 = (1 - fx) * (1 - fy) * (1 - fz);
    float w001 = (1 - fx) * (1 - fy) * fz;
    float w010 = (1 - fx) * fy * (1 - fz);
    float w011 = (1 - fx) * fy * fz;
    float w100 = fx * (1 - fy) * (1 - fz);
    float w101 = fx * (1 - fy) * fz;
    float w110 = fx * fy * (1 - fz);
    float w111 = fx * fy * fz;

    float acc[16];
#pragma unroll
    for (int j = 0; j < 16; ++j) acc[j] = 0.f;
    const float* fb = feats + (size_t)b * C_ * N_ + n;
#pragma unroll 8
    for (int ci = 0; ci < C_; ++ci) {
        float f = fb[(size_t)ci * N_];
#pragma unroll
        for (int j = 0; j < 16; ++j) acc[j] += f * mw[(size_t)(cbase + j) * C_ + ci];
    }
#pragma unroll
    for (int j = 0; j < 16; ++j) {
        int co = cbase + j;
        const float* xb = x2 + ((size_t)b * C_ + co) * R3_;
        float dv = xb[o000] * w000 + xb[o001] * w001 + xb[o010] * w010 + xb[o011] * w011 +
                   xb[o100] * w100 + xb[o101] * w101 + xb[o110] * w110 + xb[o111] * w111;
        float s = g[co] * rsqrtf(bv[co] + 1e-5f);
        float t = bb[co] - bm[co] * s;
        float pt = (acc[j] + mb[co]) * s + t;
        pt = fmaxf(pt, 0.f);
        out[((size_t)b * C_ + co) * N_ + n] = dv + pt;
    }
}

extern "C" void kernel_launch(void* const* d_in, const int* in_sizes, int n_in,
                              void* d_out, int out_size, void* d_ws, size_t ws_size,
                              hipStream_t stream) {
    const float* features = (const float*)d_in[0];
    const float* coords   = (const float*)d_in[1];
    const float* time_emb = (const float*)d_in[2];
    const float* conv1_w  = (const float*)d_in[3];
    const float* conv1_b  = (const float*)d_in[4];
    const float* bn1_g = (const float*)d_in[5];
    const float* bn1_b = (const float*)d_in[6];
    const float* bn1_m = (const float*)d_in[7];
    const float* bn1_v = (const float*)d_in[8];
    const float* conv2_w  = (const float*)d_in[9];
    const float* conv2_b  = (const float*)d_in[10];
    const float* bn2_g = (const float*)d_in[11];
    const float* bn2_b = (const float*)d_in[12];
    const float* bn2_m = (const float*)d_in[13];
    const float* bn2_v = (const float*)d_in[14];
    const float* mlp_w = (const float*)d_in[15];
    const float* mlp_b = (const float*)d_in[16];
    const float* bn3_g = (const float*)d_in[17];
    const float* bn3_b = (const float*)d_in[18];
    const float* bn3_m = (const float*)d_in[19];
    const float* bn3_v = (const float*)d_in[20];
    float* out = (float*)d_out;
    float* ws = (float*)d_ws;

    // workspace layout (floats)
    float* voxsum  = ws;                       // B*C*R3 = 16,777,216 (reused as conv2 out)
    float* x1      = ws + 16777216;            // 16,777,216
    float* cnt     = ws + 33554432;            // 262,144
    float* stats   = ws + 33816576;            // 64
    float* ncoords = ws + 33816640;            // 1,572,864
    // total 35,389,504 floats = 141.6 MB

    hipMemsetAsync(voxsum, 0, (size_t)16777216 * sizeof(float), stream);
    hipMemsetAsync(cnt, 0, (size_t)(262144 + 64) * sizeof(float), stream);

    k_stats_sum<<<dim3(32, B_), 256, 0, stream>>>(coords, stats);
    k_stats_max<<<dim3(32, B_), 256, 0, stream>>>(coords, stats);
    k_scatter<<<dim3(B_ * N_ / 256), 256, 0, stream>>>(features, coords, stats, voxsum, cnt,
                                                       ncoords);
    k_conv<true><<<dim3(B_ * R_, C_), 256, 0, stream>>>(voxsum, cnt, conv1_w, conv1_b, bn1_g,
                                                        bn1_b, bn1_m, bn1_v, x1);
    k_conv<false><<<dim3(B_ * R_, C_), 256, 0, stream>>>(x1, nullptr, conv2_w, conv2_b, bn2_g,
                                                         bn2_b, bn2_m, bn2_v, voxsum /* x2 */);
    k_fuse<<<dim3(B_ * N_ / 256, 4), 256, 0, stream>>>(voxsum, ncoords, features, mlp_w, mlp_b,
                                                       bn3_g, bn3_b, bn3_m, bn3_v, out);

    // pass-through outputs: coords then time_emb
    hipMemcpyAsync(out + 33554432, coords, (size_t)(B_ * 3 * N_) * sizeof(float),
                   hipMemcpyDeviceToDevice, stream);
    hipMemcpyAsync(out + 35127296, time_emb, (size_t)(B_ * 64) * sizeof(float),
                   hipMemcpyDeviceToDevice, stream);
}

// Round 2
// 2506.808 us; speedup vs baseline: 10.5878x; 10.5878x over previous
//
#include <hip/hip_runtime.h>
#include <hip/hip_bf16.h>
#include <math.h>

#define B_   8
#define C_   64
#define N_   65536
#define R_   32
#define R3_  32768
#define RP_  34
#define RP2_ 1156      // 34*34
#define RP3_ 39304     // 34^3

typedef short short8v __attribute__((ext_vector_type(8)));
typedef float floatx4 __attribute__((ext_vector_type(4)));

__device__ inline float bf2f(short u) {
    return __uint_as_float(((unsigned)(unsigned short)u) << 16);
}
__device__ inline unsigned short f2bf(float f) {
    __hip_bfloat16 h = __float2bfloat16(f);
    return *reinterpret_cast<unsigned short*>(&h);
}
__device__ inline void atomicMaxF(float* addr, float v) {
    atomicMax((unsigned int*)addr, __float_as_uint(v));
}

// ---------------- stats ----------------
__global__ __launch_bounds__(256) void k_stats_sum(const float* __restrict__ coords,
                                                   float* __restrict__ stats) {
    int b = blockIdx.y;
    int tid = threadIdx.x;
    const float* cb = coords + (size_t)b * 3 * N_;
    float sx = 0.f, sy = 0.f, sz = 0.f;
    int base = blockIdx.x * 2048;
    for (int k = 0; k < 8; ++k) {
        int n = base + k * 256 + tid;
        sx += cb[n];
        sy += cb[N_ + n];
        sz += cb[2 * N_ + n];
    }
    for (int o = 32; o > 0; o >>= 1) {
        sx += __shfl_down(sx, o);
        sy += __shfl_down(sy, o);
        sz += __shfl_down(sz, o);
    }
    if ((tid & 63) == 0) {
        atomicAdd(&stats[b * 8 + 0], sx);
        atomicAdd(&stats[b * 8 + 1], sy);
        atomicAdd(&stats[b * 8 + 2], sz);
    }
}

__global__ __launch_bounds__(256) void k_stats_max(const float* __restrict__ coords,
                                                   float* __restrict__ stats) {
    int b = blockIdx.y;
    int tid = threadIdx.x;
    const float* cb = coords + (size_t)b * 3 * N_;
    float mx = stats[b * 8 + 0] * (1.f / N_);
    float my = stats[b * 8 + 1] * (1.f / N_);
    float mz = stats[b * 8 + 2] * (1.f / N_);
    float vm = 0.f;
    int base = blockIdx.x * 2048;
    for (int k = 0; k < 8; ++k) {
        int n = base + k * 256 + tid;
        float dx = cb[n] - mx, dy = cb[N_ + n] - my, dz = cb[2 * N_ + n] - mz;
        vm = fmaxf(vm, sqrtf(dx * dx + dy * dy + dz * dz));
    }
    for (int o = 32; o > 0; o >>= 1) vm = fmaxf(vm, __shfl_down(vm, o));
    if ((tid & 63) == 0) atomicMaxF(&stats[b * 8 + 3], vm);
}

// ---------------- scatter (voxel sums, fp32 planar) ----------------
__global__ __launch_bounds__(256) void k_scatter(const float* __restrict__ feats,
                                                 const float* __restrict__ coords,
                                                 const float* __restrict__ stats,
                                                 float* __restrict__ voxsum,
                                                 float* __restrict__ cnt,
                                                 float* __restrict__ ncoords) {
    int p = blockIdx.x * 256 + threadIdx.x;
    int b = p >> 16, n = p & (N_ - 1);
    const float* cb = coords + (size_t)b * 3 * N_;
    float mx = stats[b * 8 + 0] * (1.f / N_);
    float my = stats[b * 8 + 1] * (1.f / N_);
    float mz = stats[b * 8 + 2] * (1.f / N_);
    float s2 = stats[b * 8 + 3] * 2.0f;
    float cv[3] = {cb[n] - mx, cb[N_ + n] - my, cb[2 * N_ + n] - mz};
    int id[3];
#pragma unroll
    for (int d = 0; d < 3; ++d) {
        float t = cv[d] / s2 + 0.5f;
        float nc = fminf(fmaxf(t * (float)R_, 0.f), (float)(R_ - 1));
        ncoords[((size_t)b * 3 + d) * N_ + n] = nc;
        id[d] = (int)rintf(nc);   // round-half-even == jnp.round
    }
    int vidx = id[0] * R_ * R_ + id[1] * R_ + id[2];
    atomicAdd(&cnt[(size_t)b * R3_ + vidx], 1.0f);
    float* vs = voxsum + (size_t)b * C_ * R3_ + vidx;
    const float* fb = feats + (size_t)b * C_ * N_ + n;
#pragma unroll 4
    for (int c = 0; c < C_; ++c)
        atomicAdd(&vs[(size_t)c * R3_], fb[(size_t)c * N_]);
}

// ---------------- weight prep: fp32 [co][ci][27] -> bf16 [conv][tap][co][ci]; mlp_w transpose ----------------
__global__ __launch_bounds__(256) void k_wprep(const float* __restrict__ w1,
                                               const float* __restrict__ w2,
                                               __hip_bfloat16* __restrict__ wb,
                                               const float* __restrict__ mw,
                                               float* __restrict__ mwT) {
    int i = blockIdx.x * 256 + threadIdx.x;
    if (i < 2 * 27 * 64 * 64) {
        int conv = i / 110592;
        int r = i % 110592;
        int tap = r >> 12;
        int rr = r & 4095;
        int co = rr >> 6, ci = rr & 63;
        const float* src = conv ? w2 : w1;
        wb[i] = __float2bfloat16(src[(size_t)(co * 64 + ci) * 27 + tap]);
    }
    if (i < 4096) mwT[(i & 63) * 64 + (i >> 6)] = mw[i];
}

// ---------------- voxel average -> padded channel-last bf16 ----------------
__global__ __launch_bounds__(256) void k_avg(const float* __restrict__ voxsum,
                                             const float* __restrict__ cnt,
                                             __hip_bfloat16* __restrict__ P0) {
    int p = blockIdx.x * 256 + threadIdx.x;      // 262144
    int b = p >> 15, v = p & (R3_ - 1);
    float rc = 1.0f / fmaxf(cnt[(size_t)b * R3_ + v], 1.0f);
    int d0 = v >> 10, d1 = (v >> 5) & 31, d2 = v & 31;
    unsigned* dst = (unsigned*)(P0 + ((size_t)b * RP3_ + (size_t)(d0 + 1) * RP2_ +
                                      (d1 + 1) * RP_ + (d2 + 1)) * 64);
    const float* srcp = voxsum + (size_t)b * C_ * R3_ + v;
#pragma unroll
    for (int c = 0; c < 32; ++c) {
        float f0 = srcp[(size_t)(2 * c) * R3_] * rc;
        float f1 = srcp[(size_t)(2 * c + 1) * R3_] * rc;
        dst[c] = (unsigned)f2bf(f0) | ((unsigned)f2bf(f1) << 16);
    }
}

// ---------------- implicit-GEMM bf16 MFMA conv 3x3x3 + bias + BN + SiLU ----------------
// input/output: padded channel-last bf16 [b][34][34][34][64]
// weights: bf16 [27 taps][64 co][64 ci]
__global__ __launch_bounds__(256) void k_conv_mfma(const __hip_bfloat16* __restrict__ pin,
                                                   const __hip_bfloat16* __restrict__ wt,
                                                   const float* __restrict__ cbias,
                                                   const float* __restrict__ g,
                                                   const float* __restrict__ bb,
                                                   const float* __restrict__ bm,
                                                   const float* __restrict__ bv,
                                                   __hip_bfloat16* __restrict__ pout) {
    int wg = blockIdx.x;
    int q = wg & 3, z = (wg >> 2) & 31, b = wg >> 7;
    int tid = threadIdx.x;
    int wave = tid >> 6, lane = tid & 63;
    int l15 = lane & 15, lk = lane >> 4;

    int yv[4], xv[4], Pb[4];
#pragma unroll
    for (int t = 0; t < 4; ++t) {
        yv[t] = q * 8 + wave * 2 + (t >> 1);
        xv[t] = (t & 1) * 16 + l15;
        Pb[t] = (yv[t] * RP_ + xv[t]) * 64 + lk * 8;
    }
    int Pa[4];
#pragma unroll
    for (int m = 0; m < 4; ++m) Pa[m] = (m * 16 + l15) * 64 + lk * 8;

    const __hip_bfloat16* pb = pin + (size_t)b * RP3_ * 64;
    floatx4 acc[4][4];
#pragma unroll
    for (int m = 0; m < 4; ++m)
#pragma unroll
        for (int t = 0; t < 4; ++t) acc[m][t] = (floatx4){0.f, 0.f, 0.f, 0.f};

    for (int tap = 0; tap < 27; ++tap) {
        int dz = tap / 9, dyx = tap % 9, dy = dyx / 3, dx = dyx % 3;
        const __hip_bfloat16* ptap = pb + (size_t)(((z + dz) * RP_ + dy) * RP_ + dx) * 64;
        const __hip_bfloat16* wtap = wt + tap * 4096;
#pragma unroll
        for (int ks = 0; ks < 2; ++ks) {
            short8v a[4], bfr[4];
#pragma unroll
            for (int m = 0; m < 4; ++m)
                a[m] = *(const short8v*)(wtap + Pa[m] + ks * 32);
#pragma unroll
            for (int t = 0; t < 4; ++t)
                bfr[t] = *(const short8v*)(ptap + Pb[t] + ks * 32);
#pragma unroll
            for (int m = 0; m < 4; ++m)
#pragma unroll
                for (int t = 0; t < 4; ++t)
                    acc[m][t] = __builtin_amdgcn_mfma_f32_16x16x32_bf16(a[m], bfr[t], acc[m][t],
                                                                        0, 0, 0);
        }
    }

    __hip_bfloat16* ob = pout + (size_t)b * RP3_ * 64;
#pragma unroll
    for (int m = 0; m < 4; ++m) {
        int cb = m * 16 + lk * 4;   // 4 consecutive couts per lane
        float4 g4 = *(const float4*)(g + cb);
        float4 b4 = *(const float4*)(bb + cb);
        float4 m4 = *(const float4*)(bm + cb);
        float4 v4 = *(const float4*)(bv + cb);
        float4 bi = *(const float4*)(cbias + cb);
        float s0 = g4.x * rsqrtf(v4.x + 1e-5f), s1 = g4.y * rsqrtf(v4.y + 1e-5f);
        float s2 = g4.z * rsqrtf(v4.z + 1e-5f), s3 = g4.w * rsqrtf(v4.w + 1e-5f);
        float t0 = b4.x - m4.x * s0, t1 = b4.y - m4.y * s1;
        float t2 = b4.z - m4.z * s2, t3 = b4.w - m4.w * s3;
#pragma unroll
        for (int t = 0; t < 4; ++t) {
            float r0 = (acc[m][t][0] + bi.x) * s0 + t0;
            float r1 = (acc[m][t][1] + bi.y) * s1 + t1;
            float r2 = (acc[m][t][2] + bi.z) * s2 + t2;
            float r3 = (acc[m][t][3] + bi.w) * s3 + t3;
            r0 = r0 / (1.0f + expf(-r0));
            r1 = r1 / (1.0f + expf(-r1));
            r2 = r2 / (1.0f + expf(-r2));
            r3 = r3 / (1.0f + expf(-r3));
            unsigned lo = (unsigned)f2bf(r0) | ((unsigned)f2bf(r1) << 16);
            unsigned hi = (unsigned)f2bf(r2) | ((unsigned)f2bf(r3) << 16);
            uint2 pk = {lo, hi};
            *(uint2*)(ob + (size_t)(((z + 1) * RP_ + yv[t] + 1) * RP_ + xv[t] + 1) * 64 + cb) = pk;
        }
    }
}

// ---------------- devoxelize (bf16 channel-last gather) + MLP + BN3 + ReLU + add ----------------
__global__ __launch_bounds__(256) void k_fuse(const __hip_bfloat16* __restrict__ P2,
                                              const float* __restrict__ ncoords,
                                              const float* __restrict__ feats,
                                              const float* __restrict__ mwT,
                                              const float* __restrict__ mb,
                                              const float* __restrict__ g,
                                              const float* __restrict__ bb,
                                              const float* __restrict__ bm,
                                              const float* __restrict__ bv,
                                              float* __restrict__ out) {
    int p = blockIdx.x * 256 + threadIdx.x;
    int b = p >> 16, n = p & (N_ - 1);

    float c0 = ncoords[((size_t)b * 3 + 0) * N_ + n];
    float c1 = ncoords[((size_t)b * 3 + 1) * N_ + n];
    float c2 = ncoords[((size_t)b * 3 + 2) * N_ + n];
    float fl0 = floorf(c0), fl1 = floorf(c1), fl2 = floorf(c2);
    float f0 = c0 - fl0, f1 = c1 - fl1, f2 = c2 - fl2;
    int a0 = (int)fl0, a1 = (int)fl1, a2 = (int)fl2;
    int h0 = min(a0 + 1, R_ - 1), h1 = min(a1 + 1, R_ - 1), h2 = min(a2 + 1, R_ - 1);

    int pvo[8];
    float wct[8];
    {
        int x0 = a0 + 1, x1 = h0 + 1, y0 = a1 + 1, y1 = h1 + 1, z0 = a2 + 1, z1 = h2 + 1;
        pvo[0] = (x0 * RP_ + y0) * RP_ + z0;  wct[0] = (1 - f0) * (1 - f1) * (1 - f2);
        pvo[1] = (x0 * RP_ + y0) * RP_ + z1;  wct[1] = (1 - f0) * (1 - f1) * f2;
        pvo[2] = (x0 * RP_ + y1) * RP_ + z0;  wct[2] = (1 - f0) * f1 * (1 - f2);
        pvo[3] = (x0 * RP_ + y1) * RP_ + z1;  wct[3] = (1 - f0) * f1 * f2;
        pvo[4] = (x1 * RP_ + y0) * RP_ + z0;  wct[4] = f0 * (1 - f1) * (1 - f2);
        pvo[5] = (x1 * RP_ + y0) * RP_ + z1;  wct[5] = f0 * (1 - f1) * f2;
        pvo[6] = (x1 * RP_ + y1) * RP_ + z0;  wct[6] = f0 * f1 * (1 - f2);
        pvo[7] = (x1 * RP_ + y1) * RP_ + z1;  wct[7] = f0 * f1 * f2;
    }

    float acc[64];
#pragma unroll
    for (int co = 0; co < 64; ++co) acc[co] = 0.f;

    const float* fb = feats + (size_t)b * C_ * N_ + n;
#pragma unroll 4
    for (int ci = 0; ci < 64; ++ci) {
        float f = fb[(size_t)ci * N_];
        const float* wr = mwT + ci * 64;
#pragma unroll
        for (int co = 0; co < 64; ++co) acc[co] += f * wr[co];
    }
#pragma unroll
    for (int co = 0; co < 64; ++co) {
        float s = g[co] * rsqrtf(bv[co] + 1e-5f);
        float tt = bb[co] - bm[co] * s;
        float ptv = (acc[co] + mb[co]) * s + tt;
        acc[co] = fmaxf(ptv, 0.f);
    }

    const __hip_bfloat16* vb = P2 + (size_t)b * RP3_ * 64;
#pragma unroll
    for (int k = 0; k < 8; ++k) {
        const short8v* vp = (const short8v*)(vb + (size_t)pvo[k] * 64);
        float wk = wct[k];
#pragma unroll
        for (int cj = 0; cj < 8; ++cj) {
            short8v v8 = vp[cj];
#pragma unroll
            for (int j = 0; j < 8; ++j) acc[cj * 8 + j] += wk * bf2f(v8[j]);
        }
    }
#pragma unroll
    for (int co = 0; co < 64; ++co)
        out[((size_t)b * C_ + co) * N_ + n] = acc[co];
}

// ---------------- launch ----------------
extern "C" void kernel_launch(void* const* d_in, const int* in_sizes, int n_in,
                              void* d_out, int out_size, void* d_ws, size_t ws_size,
                              hipStream_t stream) {
    const float* features = (const float*)d_in[0];
    const float* coords   = (const float*)d_in[1];
    const float* time_emb = (const float*)d_in[2];
    const float* conv1_w  = (const float*)d_in[3];
    const float* conv1_b  = (const float*)d_in[4];
    const float* bn1_g = (const float*)d_in[5];
    const float* bn1_b = (const float*)d_in[6];
    const float* bn1_m = (const float*)d_in[7];
    const float* bn1_v = (const float*)d_in[8];
    const float* conv2_w  = (const float*)d_in[9];
    const float* conv2_b  = (const float*)d_in[10];
    const float* bn2_g = (const float*)d_in[11];
    const float* bn2_b = (const float*)d_in[12];
    const float* bn2_m = (const float*)d_in[13];
    const float* bn2_v = (const float*)d_in[14];
    const float* mlp_w = (const float*)d_in[15];
    const float* mlp_b = (const float*)d_in[16];
    const float* bn3_g = (const float*)d_in[17];
    const float* bn3_b = (const float*)d_in[18];
    const float* bn3_m = (const float*)d_in[19];
    const float* bn3_v = (const float*)d_in[20];
    float* out = (float*)d_out;
    float* ws = (float*)d_ws;

    // workspace layout (float offsets)
    const size_t OFF_VOX   = 0;              // 16,777,216 f (fp32 voxel sums; later reused as P2)
    const size_t OFF_CNT   = 16777216;       // 262,144 f
    const size_t OFF_STATS = 17039360;       // 64 f
    const size_t OFF_NC    = 17039424;       // 1,572,864 f
    const size_t OFF_P0    = 18612288;       // 10,061,824 f as bf16[20,123,648]
    const size_t OFF_P1    = 28674112;       // 10,061,824 f
    const size_t OFF_WB    = 38735936;       // 110,592 f as bf16[221,184]
    const size_t OFF_MWT   = 38846528;       // 4,096 f   (end: 38,850,624 f = 155.4 MB)

    float* voxsum = ws + OFF_VOX;
    float* cnt    = ws + OFF_CNT;
    float* stats  = ws + OFF_STATS;
    float* ncrd   = ws + OFF_NC;
    __hip_bfloat16* P0 = (__hip_bfloat16*)(ws + OFF_P0);
    __hip_bfloat16* P1 = (__hip_bfloat16*)(ws + OFF_P1);
    __hip_bfloat16* P2 = (__hip_bfloat16*)(ws + OFF_VOX);   // aliases voxsum (dead after k_avg)
    __hip_bfloat16* wb = (__hip_bfloat16*)(ws + OFF_WB);
    float* mwT = ws + OFF_MWT;

    hipMemsetAsync(voxsum, 0, (size_t)16777216 * sizeof(float), stream);
    hipMemsetAsync(cnt, 0, (size_t)(262144 + 64) * sizeof(float), stream);
    hipMemsetAsync(P0, 0, (size_t)8 * RP3_ * 64 * sizeof(__hip_bfloat16), stream);
    hipMemsetAsync(P1, 0, (size_t)8 * RP3_ * 64 * sizeof(__hip_bfloat16), stream);

    k_wprep<<<dim3(864), 256, 0, stream>>>(conv1_w, conv2_w, wb, mlp_w, mwT);
    k_stats_sum<<<dim3(32, B_), 256, 0, stream>>>(coords, stats);
    k_stats_max<<<dim3(32, B_), 256, 0, stream>>>(coords, stats);
    k_scatter<<<dim3(B_ * N_ / 256), 256, 0, stream>>>(features, coords, stats, voxsum, cnt, ncrd);
    k_avg<<<dim3(B_ * R3_ / 256), 256, 0, stream>>>(voxsum, cnt, P0);
    k_conv_mfma<<<dim3(B_ * 32 * 4), 256, 0, stream>>>(P0, wb, conv1_b, bn1_g, bn1_b, bn1_m,
                                                       bn1_v, P1);
    k_conv_mfma<<<dim3(B_ * 32 * 4), 256, 0, stream>>>(P1, wb + 110592, conv2_b, bn2_g, bn2_b,
                                                       bn2_m, bn2_v, P2);
    k_fuse<<<dim3(B_ * N_ / 256), 256, 0, stream>>>(P2, ncrd, features, mwT, mlp_b, bn3_g, bn3_b,
                                                    bn3_m, bn3_v, out);

    hipMemcpyAsync(out + 33554432, coords, (size_t)(B_ * 3 * N_) * sizeof(float),
                   hipMemcpyDeviceToDevice, stream);
    hipMemcpyAsync(out + 35127296, time_emb, (size_t)(B_ * 64) * sizeof(float),
                   hipMemcpyDeviceToDevice, stream);
}

// Round 4
// 1219.078 us; speedup vs baseline: 21.7718x; 2.0563x over previous
//
#include <hip/hip_runtime.h>
#include <hip/hip_bf16.h>
#include <math.h>

#define B_   8
#define C_   64
#define N_   65536
#define R_   32
#define R3_  32768
#define RP_  34
#define RP2_ 1156      // 34*34
#define RP3_ 39304     // 34^3

typedef short short8v __attribute__((ext_vector_type(8)));
typedef float floatx4 __attribute__((ext_vector_type(4)));

__device__ inline float bf2f(short u) {
    return __uint_as_float(((unsigned)(unsigned short)u) << 16);
}
__device__ inline unsigned short f2bf(float f) {
    __hip_bfloat16 h = __float2bfloat16(f);
    return *reinterpret_cast<unsigned short*>(&h);
}
__device__ inline void atomicMaxF(float* addr, float v) {
    atomicMax((unsigned int*)addr, __float_as_uint(v));
}

// ---------------- stats ----------------
__global__ __launch_bounds__(256) void k_stats_sum(const float* __restrict__ coords,
                                                   float* __restrict__ stats) {
    int b = blockIdx.y;
    int tid = threadIdx.x;
    const float* cb = coords + (size_t)b * 3 * N_;
    float sx = 0.f, sy = 0.f, sz = 0.f;
    int base = blockIdx.x * 2048;
    for (int k = 0; k < 8; ++k) {
        int n = base + k * 256 + tid;
        sx += cb[n];
        sy += cb[N_ + n];
        sz += cb[2 * N_ + n];
    }
    for (int o = 32; o > 0; o >>= 1) {
        sx += __shfl_down(sx, o);
        sy += __shfl_down(sy, o);
        sz += __shfl_down(sz, o);
    }
    if ((tid & 63) == 0) {
        atomicAdd(&stats[b * 8 + 0], sx);
        atomicAdd(&stats[b * 8 + 1], sy);
        atomicAdd(&stats[b * 8 + 2], sz);
    }
}

__global__ __launch_bounds__(256) void k_stats_max(const float* __restrict__ coords,
                                                   float* __restrict__ stats) {
    int b = blockIdx.y;
    int tid = threadIdx.x;
    const float* cb = coords + (size_t)b * 3 * N_;
    float mx = stats[b * 8 + 0] * (1.f / N_);
    float my = stats[b * 8 + 1] * (1.f / N_);
    float mz = stats[b * 8 + 2] * (1.f / N_);
    float vm = 0.f;
    int base = blockIdx.x * 2048;
    for (int k = 0; k < 8; ++k) {
        int n = base + k * 256 + tid;
        float dx = cb[n] - mx, dy = cb[N_ + n] - my, dz = cb[2 * N_ + n] - mz;
        vm = fmaxf(vm, sqrtf(dx * dx + dy * dy + dz * dz));
    }
    for (int o = 32; o > 0; o >>= 1) vm = fmaxf(vm, __shfl_down(vm, o));
    if ((tid & 63) == 0) atomicMaxF(&stats[b * 8 + 3], vm);
}

// ---------------- feature transpose: fp32 [b][c][n] -> bf16 [b*N+n][c] ----------------
__global__ __launch_bounds__(256) void k_transpose(const float* __restrict__ feats,
                                                   unsigned short* __restrict__ featsT) {
    __shared__ float tile[64][65];
    int b = blockIdx.x >> 10;
    int n0 = (blockIdx.x & 1023) * 64;
    int t = threadIdx.x;
    {
        int c = t >> 2, x0 = (t & 3) * 16;
        const float* src = feats + ((size_t)b * 64 + c) * N_ + n0 + x0;
#pragma unroll
        for (int j = 0; j < 4; ++j) {
            float4 v = *(const float4*)(src + j * 4);
            tile[c][x0 + j * 4 + 0] = v.x;
            tile[c][x0 + j * 4 + 1] = v.y;
            tile[c][x0 + j * 4 + 2] = v.z;
            tile[c][x0 + j * 4 + 3] = v.w;
        }
    }
    __syncthreads();
    {
        int n = t >> 2, c0 = (t & 3) * 16;
        short8v s0, s1;
#pragma unroll
        for (int j = 0; j < 8; ++j) s0[j] = (short)f2bf(tile[c0 + j][n]);
#pragma unroll
        for (int j = 0; j < 8; ++j) s1[j] = (short)f2bf(tile[c0 + 8 + j][n]);
        unsigned short* dst = featsT + ((size_t)b * N_ + n0 + n) * 64 + c0;
        *(short8v*)(dst) = s0;
        *(short8v*)(dst + 8) = s1;
    }
}

// ---------------- voxel-id histogram + ncoords ----------------
__global__ __launch_bounds__(256) void k_hist(const float* __restrict__ coords,
                                              const float* __restrict__ stats,
                                              float* __restrict__ ncoords,
                                              unsigned* __restrict__ pvidx,
                                              unsigned* __restrict__ cnt) {
    int p = blockIdx.x * 256 + threadIdx.x;
    int b = p >> 16, n = p & (N_ - 1);
    const float* cb = coords + (size_t)b * 3 * N_;
    float mx = stats[b * 8 + 0] * (1.f / N_);
    float my = stats[b * 8 + 1] * (1.f / N_);
    float mz = stats[b * 8 + 2] * (1.f / N_);
    float s2 = stats[b * 8 + 3] * 2.0f;
    float cv[3] = {cb[n] - mx, cb[N_ + n] - my, cb[2 * N_ + n] - mz};
    int id[3];
#pragma unroll
    for (int d = 0; d < 3; ++d) {
        float t = cv[d] / s2 + 0.5f;
        float nc = fminf(fmaxf(t * (float)R_, 0.f), (float)(R_ - 1));
        ncoords[((size_t)b * 3 + d) * N_ + n] = nc;
        id[d] = (int)rintf(nc);   // round-half-even == jnp.round
    }
    unsigned v = (unsigned)(b * R3_ + id[0] * 1024 + id[1] * 32 + id[2]);
    pvidx[p] = v;
    atomicAdd(&cnt[v], 1u);
}

// ---------------- two-level exclusive scan over 262144 counts ----------------
__global__ __launch_bounds__(256) void k_scan1(const unsigned* __restrict__ cnt,
                                               unsigned* __restrict__ lp,
                                               unsigned* __restrict__ btot) {
    __shared__ unsigned sh[256];
    int t = threadIdx.x;
    int i0 = blockIdx.x * 1024 + t * 4;
    uint4 v = *(const uint4*)(cnt + i0);
    unsigned ts = v.x + v.y + v.z + v.w;
    sh[t] = ts;
    __syncthreads();
    for (int off = 1; off < 256; off <<= 1) {
        unsigned u = (t >= off) ? sh[t - off] : 0u;
        __syncthreads();
        sh[t] += u;
        __syncthreads();
    }
    unsigned ex = sh[t] - ts;
    uint4 o;
    o.x = ex;
    o.y = ex + v.x;
    o.z = ex + v.x + v.y;
    o.w = ex + v.x + v.y + v.z;
    *(uint4*)(lp + i0) = o;
    if (t == 255) btot[blockIdx.x] = sh[255];
}

__global__ __launch_bounds__(256) void k_scan2(unsigned* __restrict__ btot,
                                               unsigned* __restrict__ boff) {
    __shared__ unsigned sh[256];
    int t = threadIdx.x;
    unsigned ts = btot[t];
    sh[t] = ts;
    __syncthreads();
    for (int off = 1; off < 256; off <<= 1) {
        unsigned u = (t >= off) ? sh[t - off] : 0u;
        __syncthreads();
        sh[t] += u;
        __syncthreads();
    }
    boff[t] = sh[t] - ts;
}

// ---------------- rank: stable position within voxel -> order[] ----------------
__global__ __launch_bounds__(256) void k_rank(const unsigned* __restrict__ pvidx,
                                              const unsigned* __restrict__ lp,
                                              const unsigned* __restrict__ boff,
                                              unsigned* __restrict__ cnt,
                                              unsigned* __restrict__ order) {
    int p = blockIdx.x * 256 + threadIdx.x;
    unsigned v = pvidx[p];
    unsigned pos = atomicAdd(&cnt[v], 1u);
    order[lp[v] + boff[v >> 10] + pos] = (unsigned)p;
}

// ---------------- gather: wave per voxel, lane = channel; avg -> padded bf16 P0 ----------------
__global__ __launch_bounds__(256) void k_gather(const unsigned* __restrict__ order,
                                                const unsigned short* __restrict__ featsT,
                                                const unsigned* __restrict__ cnt,
                                                const unsigned* __restrict__ lp,
                                                const unsigned* __restrict__ boff,
                                                __hip_bfloat16* __restrict__ P0) {
    int gid = blockIdx.x * 256 + threadIdx.x;
    int v = gid >> 6;
    int lane = threadIdx.x & 63;
    unsigned base = lp[v] + boff[v >> 10];
    unsigned cv = cnt[v];
    float acc = 0.f;
    for (unsigned i = 0; i < cv; ++i) {
        unsigned p = order[base + i];
        acc += bf2f((short)featsT[(size_t)p * 64 + lane]);
    }
    float avg = (cv > 0) ? acc / (float)cv : 0.f;
    int b = v >> 15, loc = v & (R3_ - 1);
    int d0 = loc >> 10, d1 = (loc >> 5) & 31, d2 = loc & 31;
    P0[((size_t)b * RP3_ + (size_t)(d0 + 1) * RP2_ + (d1 + 1) * RP_ + (d2 + 1)) * 64 + lane] =
        __float2bfloat16(avg);
}

// ---------------- weight prep: fp32 [co][ci][27] -> bf16 [conv][tap][co][ci]; mlp_w transpose ----------------
__global__ __launch_bounds__(256) void k_wprep(const float* __restrict__ w1,
                                               const float* __restrict__ w2,
                                               __hip_bfloat16* __restrict__ wb,
                                               const float* __restrict__ mw,
                                               float* __restrict__ mwT) {
    int i = blockIdx.x * 256 + threadIdx.x;
    if (i < 2 * 27 * 64 * 64) {
        int conv = i / 110592;
        int r = i % 110592;
        int tap = r >> 12;
        int rr = r & 4095;
        int co = rr >> 6, ci = rr & 63;
        const float* src = conv ? w2 : w1;
        wb[i] = __float2bfloat16(src[(size_t)(co * 64 + ci) * 27 + tap]);
    }
    if (i < 4096) mwT[(i & 63) * 64 + (i >> 6)] = mw[i];
}

// ---------------- implicit-GEMM bf16 MFMA conv 3x3x3 + bias + BN + SiLU ----------------
__global__ __launch_bounds__(256) void k_conv_mfma(const __hip_bfloat16* __restrict__ pin,
                                                   const __hip_bfloat16* __restrict__ wt,
                                                   const float* __restrict__ cbias,
                                                   const float* __restrict__ g,
                                                   const float* __restrict__ bb,
                                                   const float* __restrict__ bm,
                                                   const float* __restrict__ bv,
                                                   __hip_bfloat16* __restrict__ pout) {
    int wg = blockIdx.x;
    int q = wg & 3, z = (wg >> 2) & 31, b = wg >> 7;
    int tid = threadIdx.x;
    int wave = tid >> 6, lane = tid & 63;
    int l15 = lane & 15, lk = lane >> 4;

    int yv[4], xv[4], Pb[4];
#pragma unroll
    for (int t = 0; t < 4; ++t) {
        yv[t] = q * 8 + wave * 2 + (t >> 1);
        xv[t] = (t & 1) * 16 + l15;
        Pb[t] = (yv[t] * RP_ + xv[t]) * 64 + lk * 8;
    }
    int Pa[4];
#pragma unroll
    for (int m = 0; m < 4; ++m) Pa[m] = (m * 16 + l15) * 64 + lk * 8;

    const __hip_bfloat16* pb = pin + (size_t)b * RP3_ * 64;
    floatx4 acc[4][4];
#pragma unroll
    for (int m = 0; m < 4; ++m)
#pragma unroll
        for (int t = 0; t < 4; ++t) acc[m][t] = (floatx4){0.f, 0.f, 0.f, 0.f};

    for (int tap = 0; tap < 27; ++tap) {
        int dz = tap / 9, dyx = tap % 9, dy = dyx / 3, dx = dyx % 3;
        const __hip_bfloat16* ptap = pb + (size_t)(((z + dz) * RP_ + dy) * RP_ + dx) * 64;
        const __hip_bfloat16* wtap = wt + tap * 4096;
#pragma unroll
        for (int ks = 0; ks < 2; ++ks) {
            short8v a[4], bfr[4];
#pragma unroll
            for (int m = 0; m < 4; ++m)
                a[m] = *(const short8v*)(wtap + Pa[m] + ks * 32);
#pragma unroll
            for (int t = 0; t < 4; ++t)
                bfr[t] = *(const short8v*)(ptap + Pb[t] + ks * 32);
#pragma unroll
            for (int m = 0; m < 4; ++m)
#pragma unroll
                for (int t = 0; t < 4; ++t)
                    acc[m][t] = __builtin_amdgcn_mfma_f32_16x16x32_bf16(a[m], bfr[t], acc[m][t],
                                                                        0, 0, 0);
        }
    }

    __hip_bfloat16* ob = pout + (size_t)b * RP3_ * 64;
#pragma unroll
    for (int m = 0; m < 4; ++m) {
        int cb = m * 16 + lk * 4;
        float4 g4 = *(const float4*)(g + cb);
        float4 b4 = *(const float4*)(bb + cb);
        float4 m4 = *(const float4*)(bm + cb);
        float4 v4 = *(const float4*)(bv + cb);
        float4 bi = *(const float4*)(cbias + cb);
        float s0 = g4.x * rsqrtf(v4.x + 1e-5f), s1 = g4.y * rsqrtf(v4.y + 1e-5f);
        float s2 = g4.z * rsqrtf(v4.z + 1e-5f), s3 = g4.w * rsqrtf(v4.w + 1e-5f);
        float t0 = b4.x - m4.x * s0, t1 = b4.y - m4.y * s1;
        float t2 = b4.z - m4.z * s2, t3 = b4.w - m4.w * s3;
#pragma unroll
        for (int t = 0; t < 4; ++t) {
            float r0 = (acc[m][t][0] + bi.x) * s0 + t0;
            float r1 = (acc[m][t][1] + bi.y) * s1 + t1;
            float r2 = (acc[m][t][2] + bi.z) * s2 + t2;
            float r3 = (acc[m][t][3] + bi.w) * s3 + t3;
            r0 = r0 / (1.0f + expf(-r0));
            r1 = r1 / (1.0f + expf(-r1));
            r2 = r2 / (1.0f + expf(-r2));
            r3 = r3 / (1.0f + expf(-r3));
            unsigned lo = (unsigned)f2bf(r0) | ((unsigned)f2bf(r1) << 16);
            unsigned hi = (unsigned)f2bf(r2) | ((unsigned)f2bf(r3) << 16);
            uint2 pk = {lo, hi};
            *(uint2*)(ob + (size_t)(((z + 1) * RP_ + yv[t] + 1) * RP_ + xv[t] + 1) * 64 + cb) = pk;
        }
    }
}

// ---------------- devoxelize + MLP + BN3 + ReLU + add ----------------
__global__ __launch_bounds__(256) void k_fuse(const __hip_bfloat16* __restrict__ P2,
                                              const float* __restrict__ ncoords,
                                              const float* __restrict__ feats,
                                              const float* __restrict__ mwT,
                                              const float* __restrict__ mb,
                                              const float* __restrict__ g,
                                              const float* __restrict__ bb,
                                              const float* __restrict__ bm,
                                              const float* __restrict__ bv,
                                              float* __restrict__ out) {
    int p = blockIdx.x * 256 + threadIdx.x;
    int b = p >> 16, n = p & (N_ - 1);

    float c0 = ncoords[((size_t)b * 3 + 0) * N_ + n];
    float c1 = ncoords[((size_t)b * 3 + 1) * N_ + n];
    float c2 = ncoords[((size_t)b * 3 + 2) * N_ + n];
    float fl0 = floorf(c0), fl1 = floorf(c1), fl2 = floorf(c2);
    float f0 = c0 - fl0, f1 = c1 - fl1, f2 = c2 - fl2;
    int a0 = (int)fl0, a1 = (int)fl1, a2 = (int)fl2;
    int h0 = min(a0 + 1, R_ - 1), h1 = min(a1 + 1, R_ - 1), h2 = min(a2 + 1, R_ - 1);

    int pvo[8];
    float wct[8];
    {
        int x0 = a0 + 1, x1 = h0 + 1, y0 = a1 + 1, y1 = h1 + 1, z0 = a2 + 1, z1 = h2 + 1;
        pvo[0] = (x0 * RP_ + y0) * RP_ + z0;  wct[0] = (1 - f0) * (1 - f1) * (1 - f2);
        pvo[1] = (x0 * RP_ + y0) * RP_ + z1;  wct[1] = (1 - f0) * (1 - f1) * f2;
        pvo[2] = (x0 * RP_ + y1) * RP_ + z0;  wct[2] = (1 - f0) * f1 * (1 - f2);
        pvo[3] = (x0 * RP_ + y1) * RP_ + z1;  wct[3] = (1 - f0) * f1 * f2;
        pvo[4] = (x1 * RP_ + y0) * RP_ + z0;  wct[4] = f0 * (1 - f1) * (1 - f2);
        pvo[5] = (x1 * RP_ + y0) * RP_ + z1;  wct[5] = f0 * (1 - f1) * f2;
        pvo[6] = (x1 * RP_ + y1) * RP_ + z0;  wct[6] = f0 * f1 * (1 - f2);
        pvo[7] = (x1 * RP_ + y1) * RP_ + z1;  wct[7] = f0 * f1 * f2;
    }

    float acc[64];
#pragma unroll
    for (int co = 0; co < 64; ++co) acc[co] = 0.f;

    const float* fb = feats + (size_t)b * C_ * N_ + n;
#pragma unroll 4
    for (int ci = 0; ci < 64; ++ci) {
        float f = fb[(size_t)ci * N_];
        const float* wr = mwT + ci * 64;
#pragma unroll
        for (int co = 0; co < 64; ++co) acc[co] += f * wr[co];
    }
#pragma unroll
    for (int co = 0; co < 64; ++co) {
        float s = g[co] * rsqrtf(bv[co] + 1e-5f);
        float tt = bb[co] - bm[co] * s;
        float ptv = (acc[co] + mb[co]) * s + tt;
        acc[co] = fmaxf(ptv, 0.f);
    }

    const __hip_bfloat16* vb = P2 + (size_t)b * RP3_ * 64;
#pragma unroll
    for (int k = 0; k < 8; ++k) {
        const short8v* vp = (const short8v*)(vb + (size_t)pvo[k] * 64);
        float wk = wct[k];
#pragma unroll
        for (int cj = 0; cj < 8; ++cj) {
            short8v v8 = vp[cj];
#pragma unroll
            for (int j = 0; j < 8; ++j) acc[cj * 8 + j] += wk * bf2f(v8[j]);
        }
    }
#pragma unroll
    for (int co = 0; co < 64; ++co)
        out[((size_t)b * C_ + co) * N_ + n] = acc[co];
}

// ---------------- launch ----------------
extern "C" void kernel_launch(void* const* d_in, const int* in_sizes, int n_in,
                              void* d_out, int out_size, void* d_ws, size_t ws_size,
                              hipStream_t stream) {
    const float* features = (const float*)d_in[0];
    const float* coords   = (const float*)d_in[1];
    const float* time_emb = (const float*)d_in[2];
    const float* conv1_w  = (const float*)d_in[3];
    const float* conv1_b  = (const float*)d_in[4];
    const float* bn1_g = (const float*)d_in[5];
    const float* bn1_b = (const float*)d_in[6];
    const float* bn1_m = (const float*)d_in[7];
    const float* bn1_v = (const float*)d_in[8];
    const float* conv2_w  = (const float*)d_in[9];
    const float* conv2_b  = (const float*)d_in[10];
    const float* bn2_g = (const float*)d_in[11];
    const float* bn2_b = (const float*)d_in[12];
    const float* bn2_m = (const float*)d_in[13];
    const float* bn2_v = (const float*)d_in[14];
    const float* mlp_w = (const float*)d_in[15];
    const float* mlp_b = (const float*)d_in[16];
    const float* bn3_g = (const float*)d_in[17];
    const float* bn3_b = (const float*)d_in[18];
    const float* bn3_m = (const float*)d_in[19];
    const float* bn3_v = (const float*)d_in[20];
    float* out = (float*)d_out;
    float* ws = (float*)d_ws;

    // workspace layout (float offsets).
    // Region A (16,777,216 f = 67.1 MB): featsT (bf16[524288][64], full size!) until
    // k_gather finishes; then memset and reused as P1 (bf16 padded, 40.2 MB).
    const size_t OFF_A     = 0;              // 16,777,216 f
    const size_t OFF_P0    = 16777216;       // 10,061,824 f (P0, later reused as P2)
    const size_t OFF_NC    = 26839040;       // 1,572,864 f
    const size_t OFF_PV    = 28411904;       // 524,288 u32
    const size_t OFF_ORD   = 28936192;       // 524,288 u32
    const size_t OFF_CNT   = 29460480;       // 262,144 u32
    const size_t OFF_LP    = 29722624;       // 262,144 u32
    const size_t OFF_BT    = 29984768;       // 256 u32
    const size_t OFF_BOFF  = 29985024;       // 256 u32
    const size_t OFF_STATS = 29985280;       // 64 f
    const size_t OFF_WB    = 29985344;       // 110,592 f (bf16 x 221,184)
    const size_t OFF_MWT   = 30095936;       // 4,096 f   end: 30,100,032 f = 120.4 MB

    unsigned short* featsT = (unsigned short*)(ws + OFF_A);
    __hip_bfloat16* P1 = (__hip_bfloat16*)(ws + OFF_A);
    __hip_bfloat16* P0 = (__hip_bfloat16*)(ws + OFF_P0);
    __hip_bfloat16* P2 = (__hip_bfloat16*)(ws + OFF_P0);
    float* ncrd  = ws + OFF_NC;
    unsigned* pvidx = (unsigned*)(ws + OFF_PV);
    unsigned* order = (unsigned*)(ws + OFF_ORD);
    unsigned* cnt   = (unsigned*)(ws + OFF_CNT);
    unsigned* lp    = (unsigned*)(ws + OFF_LP);
    unsigned* btot  = (unsigned*)(ws + OFF_BT);
    unsigned* boff  = (unsigned*)(ws + OFF_BOFF);
    float* stats = ws + OFF_STATS;
    __hip_bfloat16* wb = (__hip_bfloat16*)(ws + OFF_WB);
    float* mwT = ws + OFF_MWT;

    hipMemsetAsync(cnt, 0, 262144 * sizeof(unsigned), stream);
    hipMemsetAsync(stats, 0, 64 * sizeof(float), stream);
    hipMemsetAsync(P0, 0, (size_t)B_ * RP3_ * 64 * sizeof(__hip_bfloat16), stream);

    k_wprep<<<dim3(864), 256, 0, stream>>>(conv1_w, conv2_w, wb, mlp_w, mwT);
    k_stats_sum<<<dim3(32, B_), 256, 0, stream>>>(coords, stats);
    k_stats_max<<<dim3(32, B_), 256, 0, stream>>>(coords, stats);
    k_transpose<<<dim3(B_ * 1024), 256, 0, stream>>>(features, featsT);
    k_hist<<<dim3(B_ * N_ / 256), 256, 0, stream>>>(coords, stats, ncrd, pvidx, cnt);
    k_scan1<<<dim3(256), 256, 0, stream>>>(cnt, lp, btot);
    hipMemsetAsync(cnt, 0, 262144 * sizeof(unsigned), stream);   // reuse as rank counters
    k_scan2<<<dim3(1), 256, 0, stream>>>(btot, boff);
    k_rank<<<dim3(B_ * N_ / 256), 256, 0, stream>>>(pvidx, lp, boff, cnt, order);
    k_gather<<<dim3(B_ * R3_ / 4), 256, 0, stream>>>(order, featsT, cnt, lp, boff, P0);

    // featsT dead; zero region A for P1 halo, then convs
    hipMemsetAsync(P1, 0, (size_t)B_ * RP3_ * 64 * sizeof(__hip_bfloat16), stream);
    k_conv_mfma<<<dim3(B_ * 32 * 4), 256, 0, stream>>>(P0, wb, conv1_b, bn1_g, bn1_b, bn1_m,
                                                       bn1_v, P1);
    k_conv_mfma<<<dim3(B_ * 32 * 4), 256, 0, stream>>>(P1, wb + 110592, conv2_b, bn2_g, bn2_b,
                                                       bn2_m, bn2_v, P2);
    k_fuse<<<dim3(B_ * N_ / 256), 256, 0, stream>>>(P2, ncrd, features, mwT, mlp_b, bn3_g, bn3_b,
                                                    bn3_m, bn3_v, out);

    hipMemcpyAsync(out + 33554432, coords, (size_t)(B_ * 3 * N_) * sizeof(float),
                   hipMemcpyDeviceToDevice, stream);
    hipMemcpyAsync(out + 35127296, time_emb, (size_t)(B_ * 64) * sizeof(float),
                   hipMemcpyDeviceToDevice, stream);
}